// Round 3
// baseline (166.182 us; speedup 1.0000x reference)
//
#include <hip/hip_runtime.h>

#define DIM   256
#define CLS   512
#define NGF   32640
#define NQ    (NGF / 4)   // 8160 float4 quads per class
#define NITER 9
#define RSH   288   // sS row stride in h16  (4 parts * 72; 576 B)
#define PSH   72    // part stride in h16 (64 data + 8 pad -> 36 dwords, +4 bank shift/part)

typedef _Float16 h16;
typedef __attribute__((ext_vector_type(2))) _Float16 h16x2;

__device__ __forceinline__ float dot2f(unsigned a, unsigned b, float c) {
#if __has_builtin(__builtin_amdgcn_fdot2)
    return __builtin_amdgcn_fdot2(__builtin_bit_cast(h16x2, a),
                                  __builtin_bit_cast(h16x2, b), c, false);
#else
    h16x2 av = __builtin_bit_cast(h16x2, a);
    h16x2 bv = __builtin_bit_cast(h16x2, b);
    return fmaf((float)av[0], (float)bv[0], fmaf((float)av[1], (float)bv[1], c));
#endif
}

// largest i with off(i) = i*(511-i)/2 <= p   (strict-upper triu row index)
__device__ __forceinline__ int row_of(int p) {
    int i = (int)(255.5f - sqrtf(65280.25f - 2.0f * (float)p));
    i = i < 0 ? 0 : (i > 254 ? 254 : i);
    while ((i + 1) * (510 - i) / 2 <= p) ++i;
    while (i > 0 && i * (511 - i) / 2 > p) --i;
    return i;
}

__device__ __forceinline__ int cidx(int m) { return (m >> 6) * PSH + (m & 63); }

__global__ void __launch_bounds__(1024, 4)
cayley_kernel(const float* __restrict__ x, const float* __restrict__ W,
              float* __restrict__ out) {
    extern __shared__ char smem[];
    h16*   sS  = (h16*)smem;                              // 256*288*2 = 147456 B
    h16*   sy0 = (h16*)(smem + DIM * RSH * 2);            // 4*72*2 = 576 B
    h16*   sy1 = sy0 + 4 * PSH;                           // 576 B
    float* sx  = (float*)(smem + DIM * RSH * 2 + 2 * 4 * PSH * 2); // 1024 B

    const int tid = threadIdx.x;
    const int r   = tid >> 2;        // row 0..255
    const int p   = tid & 3;         // part 0..3 (cols 64p..64p+63)
    const int c0  = blockIdx.x;
    const int c1  = blockIdx.x + 256;

    uint4  sreg[8];                  // this thread's S[r][64p..64p+63] (f16)
    float4 wpre[8];                  // prefetched W[c1] quads

    auto scatter = [&](int q, float4 w4) {
        float wv[4] = {w4.x, w4.y, w4.z, w4.w};
        int p0 = q * 4;
        #pragma unroll
        for (int e = 0; e < 4; ++e) {
            int pp = p0 + e;
            int i  = row_of(pp);
            int j  = pp - i * (511 - i) / 2 + i + 1;
            float s = 0.5f * wv[e];
            sS[i * RSH + cidx(j)] = (h16)s;       // S[i][j] = +0.5 w
            sS[j * RSH + cidx(i)] = (h16)(-s);    // S[j][i] = -0.5 w
        }
    };

    const uint4* rowp = (const uint4*)(sS + r * RSH + p * PSH);

    auto iterate = [&](int c, float xr) {
        h16* ycur = sy0;
        h16* ynxt = sy1;
        for (int it = 0; it < NITER; ++it) {
            const uint4* yp = (const uint4*)(ycur + p * PSH);
            float a0 = 0.f, a1 = 0.f, a2 = 0.f, a3 = 0.f;
            #pragma unroll
            for (int k = 0; k < 8; ++k) {
                uint4 yv = yp[k];
                a0 = dot2f(sreg[k].x, yv.x, a0);
                a1 = dot2f(sreg[k].y, yv.y, a1);
                a2 = dot2f(sreg[k].z, yv.z, a2);
                a3 = dot2f(sreg[k].w, yv.w, a3);
            }
            float v = (a0 + a1) + (a2 + a3);      // partial (S y)_r
            v += __shfl_xor(v, 1);
            v += __shfl_xor(v, 2);                // full (S y)_r on all 4 lanes
            if (it < NITER - 1) {
                if (p == 0) ynxt[cidx(r)] = (h16)(xr - v);
                h16* t = ycur; ycur = ynxt; ynxt = t;
                __syncthreads();
            } else {
                if (p == 0) out[(size_t)r * CLS + c] = xr - 2.0f * v;  // out = 2y - x
            }
        }
    };

    // ================= class A =================
    if (tid < DIM) {
        float xv = x[(size_t)tid * CLS + c0];
        sx[tid] = xv;
        sy0[cidx(tid)] = (h16)xv;
        sS[tid * RSH + cidx(tid)] = (h16)0.f;     // zero diagonal
    }
    const float4* WA = (const float4*)(W + (size_t)c0 * NGF);
    const float4* WB = (const float4*)(W + (size_t)c1 * NGF);
    #pragma unroll
    for (int k = 0; k < 8; ++k) {
        int q = tid + 1024 * k;
        if (q < NQ) scatter(q, WA[q]);            // coalesced read, LDS scatter
    }
    __syncthreads();

    #pragma unroll
    for (int k = 0; k < 8; ++k) sreg[k] = rowp[k];   // one-time S -> regs
    #pragma unroll
    for (int k = 0; k < 8; ++k) {                    // prefetch class-B W (in flight
        int q = tid + 1024 * k;                      //  during A's iterations)
        wpre[k] = (q < NQ) ? WB[q] : float4{0.f, 0.f, 0.f, 0.f};
    }
    float xr = sx[r];
    iterate(c0, xr);

    // ================= class B =================
    __syncthreads();                              // A's last y-read complete
    if (tid < DIM) {
        float xv = x[(size_t)tid * CLS + c1];
        sx[tid] = xv;
        sy0[cidx(tid)] = (h16)xv;
        // diagonal in sS is still zero (scatter never touches it)
    }
    #pragma unroll
    for (int k = 0; k < 8; ++k) {
        int q = tid + 1024 * k;
        if (q < NQ) scatter(q, wpre[k]);
    }
    __syncthreads();

    #pragma unroll
    for (int k = 0; k < 8; ++k) sreg[k] = rowp[k];
    xr = sx[r];
    iterate(c1, xr);
}

extern "C" void kernel_launch(void* const* d_in, const int* in_sizes, int n_in,
                              void* d_out, int out_size, void* d_ws, size_t ws_size,
                              hipStream_t stream) {
    const float* x = (const float*)d_in[0];
    const float* W = (const float*)d_in[1];
    float* out = (float*)d_out;

    const size_t smem = (size_t)DIM * RSH * 2 + 2 * 4 * PSH * 2 + DIM * 4; // 149632 B
    hipFuncSetAttribute((const void*)cayley_kernel,
                        hipFuncAttributeMaxDynamicSharedMemorySize, (int)smem);
    hipLaunchKernelGGL(cayley_kernel, dim3(CLS / 2), dim3(1024), smem, stream, x, W, out);
}